// Round 1
// baseline (383.379 us; speedup 1.0000x reference)
//
#include <hip/hip_runtime.h>
#include <hip/hip_bf16.h>

// Problem constants (from setup_inputs: B=16, L=4096, D=1024)
constexpr int B = 16;
constexpr int L = 4096;
constexpr int D = 1024;
constexpr int P = (L - 2) / 2;  // 2047 positions

// One block of 256 threads per (b, p) output row.
// Each thread handles 4 consecutive channels (float4).
__global__ __launch_bounds__(256) void gated_cnn_kernel(
    const float* __restrict__ X,
    const float* __restrict__ G,
    const float* __restrict__ Gb,
    float* __restrict__ out) {
  const int idx = blockIdx.x;       // 0 .. B*P-1
  const int b = idx / P;
  const int p = idx - b * P;

  const float* xb    = X + (size_t)b * L * D;
  const float* left  = xb + (size_t)(2 * p + 0) * D;
  const float* mid   = xb + (size_t)(2 * p + 1) * D;
  const float* right = xb + (size_t)(2 * p + 2) * D;
  float* o = out + (size_t)idx * D;

  const int t = threadIdx.x;        // 0..255; channels d = 4t..4t+3

  // Issue all global loads up front so left/right are in flight during the
  // reduction (compiler won't hoist loads across __syncthreads).
  const float4 m  = ((const float4*)mid)[t];
  const float4 lf = ((const float4*)left)[t];
  const float4 rt = ((const float4*)right)[t];
  // G is (D,2) row-major: floats 8t..8t+7 cover d=4t..4t+3. 8 KB total, cached.
  const float4 gA = ((const float4*)G)[2 * t];      // (G[4t][0], G[4t][1], G[4t+1][0], G[4t+1][1])
  const float4 gB = ((const float4*)G)[2 * t + 1];  // (G[4t+2][0], ..., G[4t+3][1])

  // Partial dot products for the two gate logits.
  float s0 = m.x * gA.x + m.y * gA.z + m.z * gB.x + m.w * gB.z;
  float s1 = m.x * gA.y + m.y * gA.w + m.z * gB.y + m.w * gB.w;

  // 64-lane wave reduction.
  #pragma unroll
  for (int off = 32; off > 0; off >>= 1) {
    s0 += __shfl_down(s0, off, 64);
    s1 += __shfl_down(s1, off, 64);
  }

  // Combine the 4 waves through LDS.
  __shared__ float red[8];
  const int wave = t >> 6;
  if ((t & 63) == 0) {
    red[wave * 2 + 0] = s0;
    red[wave * 2 + 1] = s1;
  }
  __syncthreads();

  // Every thread computes the total + softmax (cheap; avoids another barrier).
  float t0 = red[0] + red[2] + red[4] + red[6] + Gb[0];
  float t1 = red[1] + red[3] + red[5] + red[7] + Gb[1];
  const float mx = fmaxf(t0, t1);
  const float e0 = __expf(t0 - mx);
  const float e1 = __expf(t1 - mx);
  const float inv = 1.0f / (e0 + e1);
  const float g0 = e0 * inv;
  const float g1 = e1 * inv;

  float4 r;
  r.x = lf.x * g0 + rt.x * g1;
  r.y = lf.y * g0 + rt.y * g1;
  r.z = lf.z * g0 + rt.z * g1;
  r.w = lf.w * g0 + rt.w * g1;
  ((float4*)o)[t] = r;
}

extern "C" void kernel_launch(void* const* d_in, const int* in_sizes, int n_in,
                              void* d_out, int out_size, void* d_ws, size_t ws_size,
                              hipStream_t stream) {
  const float* X  = (const float*)d_in[0];
  const float* G  = (const float*)d_in[1];
  const float* Gb = (const float*)d_in[2];
  float* out = (float*)d_out;

  gated_cnn_kernel<<<dim3(B * P), dim3(256), 0, stream>>>(X, G, Gb, out);
}